// Round 5
// baseline (579.758 us; speedup 1.0000x reference)
//
#include <hip/hip_runtime.h>

typedef _Float16 f16;
typedef _Float16 f16x8 __attribute__((ext_vector_type(8)));
typedef float f32x4 __attribute__((ext_vector_type(4)));
typedef unsigned long long u64;
typedef unsigned u32;

// dims
#define BB 128
#define TT 128
#define IIN 512
#define HHID 512
#define EEX 256

#define AL __ATOMIC_RELAXED
#define SCA __HIP_MEMORY_SCOPE_AGENT

// ---------------- prep: fp32 -> fp16 conversions + tag zeroing ----------------
__global__ void prep_kernel(const float* __restrict__ x,
    const float* __restrict__ W_ir, const float* __restrict__ W_iz, const float* __restrict__ W_in,
    const float* __restrict__ W_hr, const float* __restrict__ W_hz, const float* __restrict__ W_hn,
    f16* __restrict__ xb, f16* __restrict__ WiCat, f16* __restrict__ WhCat,
    u32* __restrict__ tags)
{
  size_t idx = (size_t)blockIdx.x * 256 + threadIdx.x;

  const size_t NX = (size_t)TT * BB * (IIN / 8);         // 1,048,576 chunks of 8
  const size_t NW = (size_t)2 * 1536 * (512 / 8);        // 196,608 per weight set
  if (idx < NX) {
    int t = (int)(idx / (BB * 64));
    int rem = (int)(idx % (BB * 64));
    int b = rem >> 6;
    int k0 = (rem & 63) * 8;
    const float* src = x + ((size_t)b * TT + t) * IIN + k0;
    f16x8 v;
#pragma unroll
    for (int j = 0; j < 8; ++j) v[j] = (f16)src[j];
    *(f16x8*)(xb + ((size_t)t * BB + b) * IIN + k0) = v;
  } else if (idx < NX + 2 * NW) {
    size_t w = idx - NX;
    bool isI = w < NW;
    size_t w2 = isI ? w : w - NW;
    int l = (int)(w2 / (1536 * 64));
    int rem = (int)(w2 % (1536 * 64));
    int n = rem >> 6;
    int k0 = (rem & 63) * 8;
    int g = n >> 9, j = n & 511;
    const float* W = isI ? (g == 0 ? W_ir : (g == 1 ? W_iz : W_in))
                         : (g == 0 ? W_hr : (g == 1 ? W_hz : W_hn));
    const float* src = W + ((size_t)l * 512 + j) * 512 + k0;
    f16x8 v;
#pragma unroll
    for (int jj = 0; jj < 8; ++jj) v[jj] = (f16)src[jj];
    f16* dst = isI ? WiCat : WhCat;
    *(f16x8*)(dst + ((size_t)l * 1536 + n) * 512 + k0) = v;
  } else if (idx < NX + 2 * NW + 131072) {
    // zero all step tags: [2][T][8][64] u32 (coherent stores so fused sc-loads see them)
    size_t z = idx - (NX + 2 * NW);
    __hip_atomic_store(tags + z, 0u, AL, SCA);
  }
}

// ---------------- er[l][b][h] = sum_e extra[b][e] * W_er[l][h][e] (f32) ----------------
__global__ void er_kernel(const float* __restrict__ extra, const float* __restrict__ W_er,
                          float* __restrict__ er)
{
  int idx = blockIdx.x * 256 + threadIdx.x;   // 2*128*512 = 131072
  int l = idx >> 16;
  int b = (idx >> 9) & 127;
  int h = idx & 511;
  const float* e = extra + (size_t)b * EEX;
  const float* w = W_er + ((size_t)l * 512 + h) * EEX;
  float acc = 0.f;
#pragma unroll 4
  for (int k = 0; k < EEX; k += 4)
    acc += e[k] * w[k] + e[k + 1] * w[k + 1] + e[k + 2] * w[k + 2] + e[k + 3] * w[k + 3];
  er[idx] = acc;
}

// ---------------- fused 2-layer recurrence ----------------
// 256 blocks x 256 threads (4 waves, 1 wave/SIMD).
// layer = bid>>7, cluster c = (bid>>4)&7 (16 batch rows), slice s = bid&15 (32 hid cols).
// Exchange: t-indexed data slots hx[layer][t][128 rows][256 u32] (u32 = 2 f16) +
// per-producer-WAVE tags tags[layer][t][c][s*4+w] = t+1, stored after that wave's
// s_waitcnt vmcnt(0) (vmcnt is wave-wide -> covers all 64 lanes' data stores).
// Consumers: every wave's 64 lanes poll the cluster's 64 tags in parallel (layer-1
// additionally polls layer-0's step-(t+1) tags), then load data immediately (no barrier).
// 2 barriers/step. No atomic RMW anywhere in the step loop.
__global__ __launch_bounds__(256, 1) void fused_recur(
    const f16* __restrict__ WiCat,   // [2][1536][512]
    const f16* __restrict__ WhCat,   // [2][1536][512]
    const f16* __restrict__ xb,      // [T*128][512]
    const float* __restrict__ er,    // [2][128][512]
    const float* __restrict__ b_ir, const float* __restrict__ b_iz, const float* __restrict__ b_in,
    float* __restrict__ outs,        // [128][T][512]
    float* __restrict__ hfin,        // [2][128][512]
    u32* __restrict__ hx0,           // [T][128][256] u32
    u32* __restrict__ hx1,           // [T][128][256] u32
    u32* __restrict__ tags)          // [2][T][8][64] u32
{
  const int tid = threadIdx.x;
  const int wave = tid >> 6, lane = tid & 63;
  const int bid = blockIdx.x;
  const int layer = bid >> 7;
  const int c = (bid >> 4) & 7;
  const int s = bid & 15;
  const int r16 = lane & 15, khi = lane >> 4;

  __shared__ f16 hL[16 * 520];        // h state, padded rows (520 f16)
  __shared__ f16 xL[16 * 520];        // input rows
  __shared__ float preH[6][16][17];   // h @ Wh^T partials (96 gate cols)
  __shared__ float preX[6][16][17];   // inp @ Wi^T partials

  // ---- pinned weight fragments: waves 0,1 -> Wh ; waves 2,3 -> Wi ----
  const bool isWi = wave >= 2;
  const int tb = (wave & 1) * 3;
  const f16* Wsrc = (isWi ? WiCat : WhCat) + (size_t)layer * 1536 * 512;
  f16x8 wf[3][16];
#pragma unroll
  for (int ti = 0; ti < 3; ++ti) {
    int gcl = (tb + ti) * 16 + r16;   // local gate col 0..95
    int g = gcl >> 5, cig = gcl & 31;
    const f16* wr = Wsrc + (size_t)(g * 512 + s * 32 + cig) * 512 + khi * 8;
#pragma unroll
    for (int cc = 0; cc < 16; ++cc) wf[ti][cc] = *(const f16x8*)(wr + cc * 32);
  }
#pragma unroll
  for (int ti = 0; ti < 3; ++ti)
#pragma unroll
    for (int cc = 0; cc < 16; ++cc)
      asm volatile("" : "+v"(wf[ti][cc]));

  // ---- zero h state ----
  {
    f16x8 z;
#pragma unroll
    for (int j = 0; j < 8; ++j) z[j] = (f16)0.f;
    for (int i = tid; i < 16 * 520 / 8; i += 256) ((f16x8*)hL)[i] = z;
  }

  // ---- blend mapping: thread owns (row, cols j0..j0+1) of the 16x32 slice ----
  const int row = tid >> 4, p = tid & 15;
  const int gr = c * 16 + row;
  const int j0 = 2 * p;
  float cbr[2], cbz[2], cbn[2];
#pragma unroll
  for (int e = 0; e < 2; ++e) {
    int jg = s * 32 + j0 + e;
    cbr[e] = b_ir[layer * 512 + jg] + er[((size_t)layer * 128 + gr) * 512 + jg];
    cbz[e] = b_iz[layer * 512 + jg];
    cbn[e] = b_in[layer * 512 + jg];
  }
  float hreg0 = 0.f, hreg1 = 0.f;   // fp32 master h (register-resident)

  u32* hxOwn = layer ? hx1 : hx0;
  u32* tagOwn = tags + (size_t)layer * TT * 8 * 64;
  const u32* tag0 = tags;           // layer-0 tag region

  // ---- initial input (t=0) -> xL ----
  if (layer == 0) {
    const u64* sx = (const u64*)xb + ((size_t)0 * 128 + c * 16) * 128;
    u64 xr0[8];
#pragma unroll
    for (int u = 0; u < 8; ++u) xr0[u] = sx[tid + 256 * u];
#pragma unroll
    for (int u = 0; u < 8; ++u) {
      int i = tid + 256 * u, r = i >> 7, q = i & 127;
      *(u64*)(xL + r * 520 + q * 4) = xr0[u];
    }
  } else {
    const u32* tp = tag0 + ((size_t)0 * 8 + c) * 64 + lane;
    while (__hip_atomic_load(tp, AL, SCA) != 1u) {}
    const u64* sx = (const u64*)hx0 + ((size_t)0 * 128 + c * 16) * 128;
    u64 xv0[8];
#pragma unroll
    for (int u = 0; u < 8; ++u)
      xv0[u] = __hip_atomic_load(sx + tid + 256 * u, AL, SCA);
#pragma unroll
    for (int u = 0; u < 8; ++u) {
      int i = tid + 256 * u, r = i >> 7, q = i & 127;
      *(u64*)(xL + r * 520 + q * 4) = xv0[u];
    }
  }
  __syncthreads();

  for (int t = 0; t < TT; ++t) {
    // ---- A: MFMA ----
    const f16* aL = isWi ? xL : hL;
    f32x4 ac0 = {0.f, 0.f, 0.f, 0.f}, ac1 = ac0, ac2 = ac0;
#pragma unroll
    for (int cc = 0; cc < 16; ++cc) {
      f16x8 a = *(const f16x8*)(aL + r16 * 520 + cc * 32 + khi * 8);
      ac0 = __builtin_amdgcn_mfma_f32_16x16x32_f16(a, wf[0][cc], ac0, 0, 0, 0);
      ac1 = __builtin_amdgcn_mfma_f32_16x16x32_f16(a, wf[1][cc], ac1, 0, 0, 0);
      ac2 = __builtin_amdgcn_mfma_f32_16x16x32_f16(a, wf[2][cc], ac2, 0, 0, 0);
    }
    {
      float (*pd)[16][17] = isWi ? preX : preH;
#pragma unroll
      for (int v = 0; v < 4; ++v) {
        pd[tb + 0][khi * 4 + v][r16] = ac0[v];
        pd[tb + 1][khi * 4 + v][r16] = ac1[v];
        pd[tb + 2][khi * 4 + v][r16] = ac2[v];
      }
    }
    __syncthreads();   // C: pre ready; hL/xL free

    // ---- D: blend + data store ----
    float hn[2];
#pragma unroll
    for (int e = 0; e < 2; ++e) {
      int j = j0 + e;
      int jz = 32 + j, jn = 64 + j;
      float sr = preX[j >> 4][row][j & 15] + cbr[e] + preH[j >> 4][row][j & 15];
      float sz = preX[jz >> 4][row][jz & 15] + cbz[e] + preH[jz >> 4][row][jz & 15];
      float pxn = preX[jn >> 4][row][jn & 15] + cbn[e];
      float phn = preH[jn >> 4][row][jn & 15];
      float rg = 1.f / (1.f + __expf(-sr));
      float zg = 1.f / (1.f + __expf(-sz));
      float xn = pxn + rg * phn;
      xn = fminf(15.f, fmaxf(-15.f, xn));
      float e2 = __expf(2.f * xn);
      float nn = (e2 - 1.f) / (e2 + 1.f);
      float hold = e ? hreg1 : hreg0;
      float hv = (1.f - zg) * nn + zg * hold;
      if (e) hreg1 = hv; else hreg0 = hv;
      hn[e] = hv;
    }
    {
      union { f16 h2[2]; u32 u; } pk;
      pk.h2[0] = (f16)hn[0]; pk.h2[1] = (f16)hn[1];
      __hip_atomic_store(hxOwn + ((size_t)t * 128 + gr) * 256 + s * 16 + p, pk.u, AL, SCA);
    }
    if (layer == 1) {
      float* o = outs + ((size_t)gr * TT + t) * 512 + s * 32 + j0;
      o[0] = hn[0]; o[1] = hn[1];
    }
    if (t == TT - 1) {
      float* hf = hfin + ((size_t)layer * 128 + gr) * 512 + s * 32 + j0;
      hf[0] = hn[0]; hf[1] = hn[1];
    }

    // ---- E/G: wave-level ack + wave tag (no barrier, no RMW) ----
    if (layer == 0 || t < TT - 1) {
      asm volatile("s_waitcnt vmcnt(0)" ::: "memory");
      if (lane == 0)
        __hip_atomic_store(tagOwn + ((size_t)t * 8 + c) * 64 + s * 4 + wave,
                           (u32)(t + 1), AL, SCA);
    }
    if (t == TT - 1) break;

    // ---- layer-0: issue xb[t+1] prefetch (overlaps poll) ----
    u64 xr[8];
    if (layer == 0) {
      const u64* sx = (const u64*)xb + ((size_t)(t + 1) * 128 + c * 16) * 128;
#pragma unroll
      for (int u = 0; u < 8; ++u) xr[u] = sx[tid + 256 * u];
    }

    // ---- H: all-wave parallel tag poll (lane l watches producer-wave l) ----
    {
      const u32* tpa = tagOwn + ((size_t)t * 8 + c) * 64 + lane;
      const u32 wa = (u32)(t + 1);
      bool da = false;
      bool db = (layer == 0);
      const u32* tpb = tag0 + ((size_t)(t + 1) * 8 + c) * 64 + lane;
      const u32 wb = (u32)(t + 2);
      while (!(da && db)) {
        if (!da) da = (__hip_atomic_load(tpa, AL, SCA) == wa);
        if (!db) db = (__hip_atomic_load(tpb, AL, SCA) == wb);
      }
    }

    // ---- J: data loads (issued per-wave right after its poll exits) ----
    u64 hv8[8];
    {
      const u64* hs = (const u64*)hxOwn + ((size_t)t * 128 + c * 16) * 128;
#pragma unroll
      for (int u = 0; u < 8; ++u)
        hv8[u] = __hip_atomic_load(hs + tid + 256 * u, AL, SCA);
    }
    u64 xv8[8];
    if (layer == 1) {
      const u64* xs = (const u64*)hx0 + ((size_t)(t + 1) * 128 + c * 16) * 128;
#pragma unroll
      for (int u = 0; u < 8; ++u)
        xv8[u] = __hip_atomic_load(xs + tid + 256 * u, AL, SCA);
    }

    // ---- K: write LDS ----
#pragma unroll
    for (int u = 0; u < 8; ++u) {
      int i = tid + 256 * u, r = i >> 7, q = i & 127;
      *(u64*)(hL + r * 520 + q * 4) = hv8[u];
    }
    if (layer == 0) {
#pragma unroll
      for (int u = 0; u < 8; ++u) {
        int i = tid + 256 * u, r = i >> 7, q = i & 127;
        *(u64*)(xL + r * 520 + q * 4) = xr[u];
      }
    } else {
#pragma unroll
      for (int u = 0; u < 8; ++u) {
        int i = tid + 256 * u, r = i >> 7, q = i & 127;
        *(u64*)(xL + r * 520 + q * 4) = xv8[u];
      }
    }
    __syncthreads();   // L: hL/xL ready for next MFMA
  }
}

// ---------------- launcher ----------------
extern "C" void kernel_launch(void* const* d_in, const int* in_sizes, int n_in,
                              void* d_out, int out_size, void* d_ws, size_t ws_size,
                              hipStream_t stream) {
  const float* x     = (const float*)d_in[0];
  const float* extra = (const float*)d_in[1];
  const float* W_ir  = (const float*)d_in[2];
  const float* b_ir  = (const float*)d_in[3];
  const float* W_hr  = (const float*)d_in[4];
  const float* W_iz  = (const float*)d_in[5];
  const float* b_iz  = (const float*)d_in[6];
  const float* W_hz  = (const float*)d_in[7];
  const float* W_in  = (const float*)d_in[8];
  const float* b_in  = (const float*)d_in[9];
  const float* W_hn  = (const float*)d_in[10];
  const float* W_er  = (const float*)d_in[11];
  float* out = (float*)d_out;

  char* ws = (char*)d_ws;
  f16* WiCat = (f16*)(ws);                    // 3,145,728 B
  f16* WhCat = (f16*)(ws + 3145728);          // 3,145,728 B
  f16* xb    = (f16*)(ws + 6291456);          // 16,777,216 B
  float* er  = (float*)(ws + 23068672);       // 524,288 B
  u32* hx0   = (u32*)(ws + 23592960);         // 16,777,216 B  [T][128][256] u32
  u32* hx1   = (u32*)(ws + 40370176);         // 16,777,216 B
  u32* tags  = (u32*)(ws + 57147392);         // 524,288 B     [2][T][8][64] u32

  prep_kernel<<<6144, 256, 0, stream>>>(x, W_ir, W_iz, W_in, W_hr, W_hz, W_hn,
                                        xb, WiCat, WhCat, tags);
  er_kernel<<<512, 256, 0, stream>>>(extra, W_er, er);

  float* outs = out;                              // [128][128][512]
  float* hfin = out + (size_t)BB * TT * HHID;     // [2][128][512]

  fused_recur<<<256, 256, 0, stream>>>(WiCat, WhCat, xb, er, b_ir, b_iz, b_in,
                                       outs, hfin, hx0, hx1, tags);
}

// Round 6
// 525.070 us; speedup vs baseline: 1.1042x; 1.1042x over previous
//
#include <hip/hip_runtime.h>

typedef _Float16 f16;
typedef _Float16 f16x8 __attribute__((ext_vector_type(8)));
typedef float f32x4 __attribute__((ext_vector_type(4)));
typedef unsigned long long u64;
typedef unsigned u32;

// dims
#define BB 128
#define TT 128
#define IIN 512
#define HHID 512
#define EEX 256

#define AL __ATOMIC_RELAXED
#define SCA __HIP_MEMORY_SCOPE_AGENT

// ---------------- prep: fp32 -> fp16 conversions + tag zeroing ----------------
__global__ void prep_kernel(const float* __restrict__ x,
    const float* __restrict__ W_ir, const float* __restrict__ W_iz, const float* __restrict__ W_in,
    const float* __restrict__ W_hr, const float* __restrict__ W_hz, const float* __restrict__ W_hn,
    f16* __restrict__ xb, f16* __restrict__ WiCat, f16* __restrict__ WhCat,
    u32* __restrict__ tags)
{
  size_t idx = (size_t)blockIdx.x * 256 + threadIdx.x;

  const size_t NX = (size_t)TT * BB * (IIN / 8);         // 1,048,576 chunks of 8
  const size_t NW = (size_t)2 * 1536 * (512 / 8);        // 196,608 per weight set
  if (idx < NX) {
    int t = (int)(idx / (BB * 64));
    int rem = (int)(idx % (BB * 64));
    int b = rem >> 6;
    int k0 = (rem & 63) * 8;
    const float* src = x + ((size_t)b * TT + t) * IIN + k0;
    f16x8 v;
#pragma unroll
    for (int j = 0; j < 8; ++j) v[j] = (f16)src[j];
    *(f16x8*)(xb + ((size_t)t * BB + b) * IIN + k0) = v;
  } else if (idx < NX + 2 * NW) {
    size_t w = idx - NX;
    bool isI = w < NW;
    size_t w2 = isI ? w : w - NW;
    int l = (int)(w2 / (1536 * 64));
    int rem = (int)(w2 % (1536 * 64));
    int n = rem >> 6;
    int k0 = (rem & 63) * 8;
    int g = n >> 9, j = n & 511;
    const float* W = isI ? (g == 0 ? W_ir : (g == 1 ? W_iz : W_in))
                         : (g == 0 ? W_hr : (g == 1 ? W_hz : W_hn));
    const float* src = W + ((size_t)l * 512 + j) * 512 + k0;
    f16x8 v;
#pragma unroll
    for (int jj = 0; jj < 8; ++jj) v[jj] = (f16)src[jj];
    f16* dst = isI ? WiCat : WhCat;
    *(f16x8*)(dst + ((size_t)l * 1536 + n) * 512 + k0) = v;
  } else if (idx < NX + 2 * NW + 32768) {
    // zero all per-block step tags: [2][T][8][16] u32
    size_t z = idx - (NX + 2 * NW);
    __hip_atomic_store(tags + z, 0u, AL, SCA);
  }
}

// ---------------- er[l][b][h] = sum_e extra[b][e] * W_er[l][h][e] (f32) ----------------
__global__ void er_kernel(const float* __restrict__ extra, const float* __restrict__ W_er,
                          float* __restrict__ er)
{
  int idx = blockIdx.x * 256 + threadIdx.x;   // 2*128*512 = 131072
  int l = idx >> 16;
  int b = (idx >> 9) & 127;
  int h = idx & 511;
  const float* e = extra + (size_t)b * EEX;
  const float* w = W_er + ((size_t)l * 512 + h) * EEX;
  float acc = 0.f;
#pragma unroll 4
  for (int k = 0; k < EEX; k += 4)
    acc += e[k] * w[k] + e[k + 1] * w[k + 1] + e[k + 2] * w[k + 2] + e[k + 3] * w[k + 3];
  er[idx] = acc;
}

// ---------------- fused 2-layer recurrence ----------------
// 256 blocks x 256 threads. layer = bid>>7, cluster c = (bid>>4)&7, slice s = bid&15.
// Exchange: t-indexed data slots hx[layer][t][128][256 u32] + ONE per-block tag
// tags[layer][t][c][s] = t+1, published by tid0 after {per-wave vmcnt(0), syncthreads}.
// Consumers: each wave polls the 16 own-cluster tags with lanes 0..15 (64 B/round);
// layer-1 lanes 16..31 poll layer-0's step-(t+1) tags. No RMW, no poll storm.
// outs/hfin HBM stores sit AFTER the tag (off the critical path). xb prefetch is
// issued at the TOP of the step so it retires before the ack's vmcnt(0).
__global__ __launch_bounds__(256, 1) void fused_recur(
    const f16* __restrict__ WiCat,   // [2][1536][512]
    const f16* __restrict__ WhCat,   // [2][1536][512]
    const f16* __restrict__ xb,      // [T*128][512]
    const float* __restrict__ er,    // [2][128][512]
    const float* __restrict__ b_ir, const float* __restrict__ b_iz, const float* __restrict__ b_in,
    float* __restrict__ outs,        // [128][T][512]
    float* __restrict__ hfin,        // [2][128][512]
    u32* __restrict__ hx0,           // [T][128][256] u32
    u32* __restrict__ hx1,           // [T][128][256] u32
    u32* __restrict__ tags)          // [2][T][8][16] u32
{
  const int tid = threadIdx.x;
  const int wave = tid >> 6, lane = tid & 63;
  const int bid = blockIdx.x;
  const int layer = bid >> 7;
  const int c = (bid >> 4) & 7;
  const int s = bid & 15;
  const int r16 = lane & 15, khi = lane >> 4;

  __shared__ f16 hL[16 * 520];        // h state, padded rows (520 f16)
  __shared__ f16 xL[16 * 520];        // input rows
  __shared__ float preH[6][16][17];   // h @ Wh^T partials (96 gate cols)
  __shared__ float preX[6][16][17];   // inp @ Wi^T partials

  // ---- pinned weight fragments: waves 0,1 -> Wh ; waves 2,3 -> Wi ----
  const bool isWi = wave >= 2;
  const int tb = (wave & 1) * 3;
  const f16* Wsrc = (isWi ? WiCat : WhCat) + (size_t)layer * 1536 * 512;
  f16x8 wf[3][16];
#pragma unroll
  for (int ti = 0; ti < 3; ++ti) {
    int gcl = (tb + ti) * 16 + r16;   // local gate col 0..95
    int g = gcl >> 5, cig = gcl & 31;
    const f16* wr = Wsrc + (size_t)(g * 512 + s * 32 + cig) * 512 + khi * 8;
#pragma unroll
    for (int cc = 0; cc < 16; ++cc) wf[ti][cc] = *(const f16x8*)(wr + cc * 32);
  }
#pragma unroll
  for (int ti = 0; ti < 3; ++ti)
#pragma unroll
    for (int cc = 0; cc < 16; ++cc)
      asm volatile("" : "+v"(wf[ti][cc]));

  // ---- zero h state ----
  {
    f16x8 z;
#pragma unroll
    for (int j = 0; j < 8; ++j) z[j] = (f16)0.f;
    for (int i = tid; i < 16 * 520 / 8; i += 256) ((f16x8*)hL)[i] = z;
  }

  // ---- blend mapping: thread owns (row, cols j0..j0+1) of the 16x32 slice ----
  const int row = tid >> 4, p = tid & 15;
  const int gr = c * 16 + row;
  const int j0 = 2 * p;
  float cbr[2], cbz[2], cbn[2];
#pragma unroll
  for (int e = 0; e < 2; ++e) {
    int jg = s * 32 + j0 + e;
    cbr[e] = b_ir[layer * 512 + jg] + er[((size_t)layer * 128 + gr) * 512 + jg];
    cbz[e] = b_iz[layer * 512 + jg];
    cbn[e] = b_in[layer * 512 + jg];
  }
  float hreg0 = 0.f, hreg1 = 0.f;   // fp32 master h (register-resident)

  u32* hxOwn = layer ? hx1 : hx0;
  u32* tagOwn = tags + (size_t)layer * TT * 8 * 16;
  const u32* tag0 = tags;           // layer-0 tag region

  // ---- initial input (t=0) -> xL ----
  if (layer == 0) {
    const u64* sx = (const u64*)xb + ((size_t)0 * 128 + c * 16) * 128;
    u64 xr0[8];
#pragma unroll
    for (int u = 0; u < 8; ++u) xr0[u] = sx[tid + 256 * u];
#pragma unroll
    for (int u = 0; u < 8; ++u) {
      int i = tid + 256 * u, r = i >> 7, q = i & 127;
      *(u64*)(xL + r * 520 + q * 4) = xr0[u];
    }
  } else {
    {
      const u32* tp = tag0 + ((size_t)0 * 8 + c) * 16;
      bool ok = false;
      while (!ok) {
        bool mine = true;
        if (lane < 16) mine = (__hip_atomic_load(tp + lane, AL, SCA) == 1u);
        ok = __all(mine);
      }
    }
    const u64* sx = (const u64*)hx0 + ((size_t)0 * 128 + c * 16) * 128;
    u64 xv0[8];
#pragma unroll
    for (int u = 0; u < 8; ++u)
      xv0[u] = __hip_atomic_load(sx + tid + 256 * u, AL, SCA);
#pragma unroll
    for (int u = 0; u < 8; ++u) {
      int i = tid + 256 * u, r = i >> 7, q = i & 127;
      *(u64*)(xL + r * 520 + q * 4) = xv0[u];
    }
  }
  __syncthreads();

  for (int t = 0; t < TT; ++t) {
    // ---- top-of-step prefetch: xb[t+1] (retires long before the ack) ----
    u64 xr[8];
    if (layer == 0 && t < TT - 1) {
      const u64* sx = (const u64*)xb + ((size_t)(t + 1) * 128 + c * 16) * 128;
#pragma unroll
      for (int u = 0; u < 8; ++u) xr[u] = sx[tid + 256 * u];
    }

    // ---- A: MFMA ----
    const f16* aL = isWi ? xL : hL;
    f32x4 ac0 = {0.f, 0.f, 0.f, 0.f}, ac1 = ac0, ac2 = ac0;
#pragma unroll
    for (int cc = 0; cc < 16; ++cc) {
      f16x8 a = *(const f16x8*)(aL + r16 * 520 + cc * 32 + khi * 8);
      ac0 = __builtin_amdgcn_mfma_f32_16x16x32_f16(a, wf[0][cc], ac0, 0, 0, 0);
      ac1 = __builtin_amdgcn_mfma_f32_16x16x32_f16(a, wf[1][cc], ac1, 0, 0, 0);
      ac2 = __builtin_amdgcn_mfma_f32_16x16x32_f16(a, wf[2][cc], ac2, 0, 0, 0);
    }
    {
      float (*pd)[16][17] = isWi ? preX : preH;
#pragma unroll
      for (int v = 0; v < 4; ++v) {
        pd[tb + 0][khi * 4 + v][r16] = ac0[v];
        pd[tb + 1][khi * 4 + v][r16] = ac1[v];
        pd[tb + 2][khi * 4 + v][r16] = ac2[v];
      }
    }
    __syncthreads();   // C: pre ready; hL/xL free

    // ---- D: blend + coherent h store ----
    float hn[2];
#pragma unroll
    for (int e = 0; e < 2; ++e) {
      int j = j0 + e;
      int jz = 32 + j, jn = 64 + j;
      float sr = preX[j >> 4][row][j & 15] + cbr[e] + preH[j >> 4][row][j & 15];
      float sz = preX[jz >> 4][row][jz & 15] + cbz[e] + preH[jz >> 4][row][jz & 15];
      float pxn = preX[jn >> 4][row][jn & 15] + cbn[e];
      float phn = preH[jn >> 4][row][jn & 15];
      float rg = 1.f / (1.f + __expf(-sr));
      float zg = 1.f / (1.f + __expf(-sz));
      float xn = pxn + rg * phn;
      xn = fminf(15.f, fmaxf(-15.f, xn));
      float e2 = __expf(2.f * xn);
      float nn = (e2 - 1.f) / (e2 + 1.f);
      float hold = e ? hreg1 : hreg0;
      float hv = (1.f - zg) * nn + zg * hold;
      if (e) hreg1 = hv; else hreg0 = hv;
      hn[e] = hv;
    }
    const bool publish = (layer == 0) || (t < TT - 1);
    if (publish) {
      union { f16 h2[2]; u32 u; } pk;
      pk.h2[0] = (f16)hn[0]; pk.h2[1] = (f16)hn[1];
      __hip_atomic_store(hxOwn + ((size_t)t * 128 + gr) * 256 + s * 16 + p, pk.u, AL, SCA);
      // ---- E: per-wave ack, block barrier, single per-block tag (plain store) ----
      asm volatile("s_waitcnt vmcnt(0)" ::: "memory");
      __syncthreads();
      if (tid == 0)
        __hip_atomic_store(tagOwn + ((size_t)t * 8 + c) * 16 + s, (u32)(t + 1), AL, SCA);
    }

    // ---- off-critical-path HBM stores ----
    if (layer == 1) {
      float* o = outs + ((size_t)gr * TT + t) * 512 + s * 32 + j0;
      o[0] = hn[0]; o[1] = hn[1];
    }
    if (t == TT - 1) {
      float* hf = hfin + ((size_t)layer * 128 + gr) * 512 + s * 32 + j0;
      hf[0] = hn[0]; hf[1] = hn[1];
      break;
    }

    // ---- H: narrow tag poll (lanes 0..15 own cluster; layer-1 lanes 16..31 -> L0 t+1) ----
    {
      const u32 wantA = (u32)(t + 1);
      const u32* tpA = tagOwn + ((size_t)t * 8 + c) * 16;
      const u32* tpB = tag0 + ((size_t)(t + 1) * 8 + c) * 16;
      bool ok = false;
      while (!ok) {
        bool mine = true;
        if (lane < 16)
          mine = (__hip_atomic_load(tpA + lane, AL, SCA) == wantA);
        else if (layer == 1 && lane < 32)
          mine = (__hip_atomic_load(tpB + (lane - 16), AL, SCA) == wantA + 1u);
        ok = __all(mine);
      }
    }

    // ---- J: data loads (per wave, immediately after its poll exits) ----
    u64 hv8[8];
    {
      const u64* hs = (const u64*)hxOwn + ((size_t)t * 128 + c * 16) * 128;
#pragma unroll
      for (int u = 0; u < 8; ++u)
        hv8[u] = __hip_atomic_load(hs + tid + 256 * u, AL, SCA);
    }
    u64 xv8[8];
    if (layer == 1) {
      const u64* xs = (const u64*)hx0 + ((size_t)(t + 1) * 128 + c * 16) * 128;
#pragma unroll
      for (int u = 0; u < 8; ++u)
        xv8[u] = __hip_atomic_load(xs + tid + 256 * u, AL, SCA);
    }

    // ---- K: write LDS ----
#pragma unroll
    for (int u = 0; u < 8; ++u) {
      int i = tid + 256 * u, r = i >> 7, q = i & 127;
      *(u64*)(hL + r * 520 + q * 4) = hv8[u];
    }
    if (layer == 0) {
#pragma unroll
      for (int u = 0; u < 8; ++u) {
        int i = tid + 256 * u, r = i >> 7, q = i & 127;
        *(u64*)(xL + r * 520 + q * 4) = xr[u];
      }
    } else {
#pragma unroll
      for (int u = 0; u < 8; ++u) {
        int i = tid + 256 * u, r = i >> 7, q = i & 127;
        *(u64*)(xL + r * 520 + q * 4) = xv8[u];
      }
    }
    __syncthreads();   // L: hL/xL ready for next MFMA
  }
}

// ---------------- launcher ----------------
extern "C" void kernel_launch(void* const* d_in, const int* in_sizes, int n_in,
                              void* d_out, int out_size, void* d_ws, size_t ws_size,
                              hipStream_t stream) {
  const float* x     = (const float*)d_in[0];
  const float* extra = (const float*)d_in[1];
  const float* W_ir  = (const float*)d_in[2];
  const float* b_ir  = (const float*)d_in[3];
  const float* W_hr  = (const float*)d_in[4];
  const float* W_iz  = (const float*)d_in[5];
  const float* b_iz  = (const float*)d_in[6];
  const float* W_hz  = (const float*)d_in[7];
  const float* W_in  = (const float*)d_in[8];
  const float* b_in  = (const float*)d_in[9];
  const float* W_hn  = (const float*)d_in[10];
  const float* W_er  = (const float*)d_in[11];
  float* out = (float*)d_out;

  char* ws = (char*)d_ws;
  f16* WiCat = (f16*)(ws);                    // 3,145,728 B
  f16* WhCat = (f16*)(ws + 3145728);          // 3,145,728 B
  f16* xb    = (f16*)(ws + 6291456);          // 16,777,216 B
  float* er  = (float*)(ws + 23068672);       // 524,288 B
  u32* hx0   = (u32*)(ws + 23592960);         // 16,777,216 B  [T][128][256] u32
  u32* hx1   = (u32*)(ws + 40370176);         // 16,777,216 B
  u32* tags  = (u32*)(ws + 57147392);         // 131,072 B     [2][T][8][16] u32

  prep_kernel<<<5760, 256, 0, stream>>>(x, W_ir, W_iz, W_in, W_hr, W_hz, W_hn,
                                        xb, WiCat, WhCat, tags);
  er_kernel<<<512, 256, 0, stream>>>(extra, W_er, er);

  float* outs = out;                              // [128][128][512]
  float* hfin = out + (size_t)BB * TT * HHID;     // [2][128][512]

  fused_recur<<<256, 256, 0, stream>>>(WiCat, WhCat, xb, er, b_ir, b_iz, b_in,
                                       outs, hfin, hx0, hx1, tags);
}